// Round 16
// baseline (610.297 us; speedup 1.0000x reference)
//
#include <hip/hip_runtime.h>
#include <math.h>

#define NNODES 50000
#define NEDGES 800000
#define FINCH 512
#define HIDC 64
#define NHEADS 8
#define OUTC 40
#define NSLOPE 0.2f
#define NSB ((NNODES + 255) / 256)

typedef unsigned short ushort;
typedef unsigned int uint;
typedef unsigned char uchar;
typedef __attribute__((ext_vector_type(8))) short bf16x8;
typedef __attribute__((ext_vector_type(4))) float f32x4;
typedef __attribute__((ext_vector_type(2))) float f32x2;

#if __has_builtin(__builtin_amdgcn_cvt_pk_f32_fp8) && __has_builtin(__builtin_amdgcn_cvt_pk_fp8_f32)
#define HAS_FP8 1
#else
#define HAS_FP8 0
#endif

static __device__ __forceinline__ float leaky(float e) { return e > 0.f ? e : NSLOPE * e; }

static __device__ __forceinline__ float bf2f(ushort u) {
    union { unsigned int i; float f; } c; c.i = ((unsigned int)u) << 16; return c.f;
}
static __device__ __forceinline__ ushort f2bf(float f) {
    union { float f; unsigned int i; } c; c.f = f;
    unsigned int r = c.i + 0x7FFF + ((c.i >> 16) & 1);  // round-nearest-even
    return (ushort)(r >> 16);
}
// order-preserving float<->uint key (for atomicMax on floats)
static __device__ __forceinline__ uint fkey(float f) {
    uint u = __float_as_uint(f);
    return (u & 0x80000000u) ? ~u : (u | 0x80000000u);
}
static __device__ __forceinline__ float fdec(uint k) {
    return __uint_as_float((k & 0x80000000u) ? (k & 0x7fffffffu) : ~k);
}

// async global->LDS 16B (wave-uniform LDS base + lane*16; per-lane global src)
static __device__ __forceinline__ void gload16(const ushort* g, ushort* l) {
    __builtin_amdgcn_global_load_lds((const __attribute__((address_space(1))) void*)g,
                                     (__attribute__((address_space(3))) void*)l, 16, 0, 0);
}

// ---------------- edge dtype detect + key init ----------------
__global__ __launch_bounds__(64) void k_detect(const int* __restrict__ ei, int* __restrict__ flag,
                                               uint* __restrict__ keys) {
    int lane = threadIdx.x;
    if (lane < 17) keys[lane] = fkey(-3.0e38f);
    int v = ei[2 * lane + 1];
    unsigned long long b = __ballot(v != 0);
    if (lane == 0) *flag = (b == 0ULL) ? 1 : 0;
}

static __device__ __forceinline__ int load_idx(const int* ei, int wide, int pos) {
    int v = wide ? ei[2 * (long long)pos] : ei[pos];
    v = v < 0 ? 0 : (v >= NNODES ? NNODES - 1 : v);
    return v;
}

// ---------------- graph build ----------------
__global__ void k_init_deg(int* __restrict__ deg) {
    int i = blockIdx.x * blockDim.x + threadIdx.x;
    if (i < NNODES) deg[i] = 1;  // self-loop
}

__global__ void k_count(const int* __restrict__ ei, const int* __restrict__ flag, int* __restrict__ deg) {
    int e = blockIdx.x * blockDim.x + threadIdx.x;
    if (e < NEDGES) {
        int d = load_idx(ei, *flag, NEDGES + e);
        atomicAdd(&deg[d], 1);
    }
}

__global__ __launch_bounds__(256) void k_bsum(const int* __restrict__ deg, int* __restrict__ bsum) {
    int i = blockIdx.x * 256 + threadIdx.x;
    int v = (i < NNODES) ? deg[i] : 0;
#pragma unroll
    for (int m = 32; m > 0; m >>= 1) v += __shfl_xor(v, m);
    __shared__ int ws[4];
    int wid = threadIdx.x >> 6, lane = threadIdx.x & 63;
    if (lane == 0) ws[wid] = v;
    __syncthreads();
    if (threadIdx.x == 0) bsum[blockIdx.x] = ws[0] + ws[1] + ws[2] + ws[3];
}

__global__ __launch_bounds__(64) void k_bscan(const int* __restrict__ bsum, int* __restrict__ bofs,
                                              int* __restrict__ offs) {
    const int lane = threadIdx.x;
    const int CH = (NSB + 63) / 64;
    int lo = lane * CH, hi = min(lo + CH, NSB);
    int s = 0;
    for (int i = lo; i < hi; i++) s += bsum[i];
    int x = s;
#pragma unroll
    for (int st = 1; st < 64; st <<= 1) { int v = __shfl_up(x, st); if (lane >= st) x += v; }
    int run = x - s;
    for (int i = lo; i < hi; i++) { bofs[i] = run; run += bsum[i]; }
    if (lane == 63) offs[NNODES] = run;
}

__global__ __launch_bounds__(256) void k_scan_final(const int* __restrict__ deg, const int* __restrict__ bofs,
                                                    int* __restrict__ offs, int* __restrict__ cur) {
    int b = blockIdx.x;
    int i = b * 256 + threadIdx.x;
    int v = (i < NNODES) ? deg[i] : 0;
    int lane = threadIdx.x & 63, wid = threadIdx.x >> 6;
    int x = v;
#pragma unroll
    for (int st = 1; st < 64; st <<= 1) { int t = __shfl_up(x, st); if (lane >= st) x += t; }
    __shared__ int ws[4];
    if (lane == 63) ws[wid] = x;
    __syncthreads();
    int wofs = 0;
#pragma unroll
    for (int w = 0; w < 4; w++) if (w < wid) wofs += ws[w];
    int excl = bofs[b] + wofs + x - v;
    if (i < NNODES) { offs[i] = excl; cur[i] = excl; }
}

__global__ void k_fill(const int* __restrict__ ei, const int* __restrict__ flag,
                       int* __restrict__ cur, int* __restrict__ csr) {
    int e = blockIdx.x * blockDim.x + threadIdx.x;
    if (e < NEDGES + NNODES) {
        int s, d;
        if (e < NEDGES) {
            int w = *flag;
            s = load_idx(ei, w, e);
            d = load_idx(ei, w, NEDGES + e);
        } else {
            s = e - NEDGES; d = s;
        }
        int pos = atomicAdd(&cur[d], 1);
        csr[pos] = s;
    }
}

// ---------------- per-head global max of src logits ----------------
template <int NH>
__global__ __launch_bounds__(256) void k_msrc(const float* __restrict__ src, uint* __restrict__ keys, int n) {
    float m = -3.0e38f;
    for (int i = blockIdx.x * 256 + threadIdx.x; i < n; i += gridDim.x * 256)
        m = fmaxf(m, src[i]);   // stride multiple of NH keeps head alignment
    __shared__ float red[256];
    red[threadIdx.x] = m;
    __syncthreads();
    for (int st = 128; st >= NH; st >>= 1) {
        if (threadIdx.x < st) red[threadIdx.x] = fmaxf(red[threadIdx.x], red[threadIdx.x + st]);
        __syncthreads();
    }
    if (threadIdx.x < NH) atomicMax(&keys[threadIdx.x], fkey(red[threadIdx.x]));
}

// ---------------- fp32 -> bf16 bulk convert ----------------
__global__ void k_f2bf(const float* __restrict__ in, ushort* __restrict__ out, int n4) {
    int i = blockIdx.x * blockDim.x + threadIdx.x;
    if (i < n4) {
        float4 v = ((const float4*)in)[i];
        ushort4 o = make_ushort4(f2bf(v.x), f2bf(v.y), f2bf(v.z), f2bf(v.w));
        ((ushort4*)out)[i] = o;
    }
}

// ---------------- W[512][512] fp32 -> Wt[512][512] bf16 transposed ----------------
__global__ __launch_bounds__(256) void k_transpose(const float* __restrict__ W, ushort* __restrict__ Wt) {
    __shared__ float tile[32][33];
    int bx = blockIdx.x, by = blockIdx.y;
    int tx = threadIdx.x & 31, ty = threadIdx.x >> 5;  // 32 x 8
#pragma unroll
    for (int i = 0; i < 4; i++)
        tile[ty + i * 8][tx] = W[(size_t)(by * 32 + ty + i * 8) * 512 + bx * 32 + tx];
    __syncthreads();
#pragma unroll
    for (int i = 0; i < 4; i++)
        Wt[(size_t)(bx * 32 + ty + i * 8) * 512 + by * 32 + tx] = f2bf(tile[tx][ty + i * 8]);
}

// ---------------- W3[512][40] fp32 -> Wt3[64][512] bf16 transposed, zero-padded ----------------
__global__ __launch_bounds__(256) void k_transpose3(const float* __restrict__ W3, ushort* __restrict__ Wt3) {
    int idx = blockIdx.x * 256 + threadIdx.x;   // 64*512 total
    int c = idx >> 9, k = idx & 511;
    Wt3[idx] = (c < OUTC) ? f2bf(W3[(size_t)k * OUTC + c]) : 0;
}

// ---------------- MFMA bf16 GEMM (layers 1-2): 64x128 tile, BK=32, 4 waves, 256 thr ----------------
// Double-buffered (24 KB LDS -> 6 blocks/CU, finer barrier domains), XCD-swizzled;
// fused alpha epilogue (asrc/adst from fp32 acc, NO atomics). CMODE: 0 = bf16 C, 1 = fp8 C.
template <int CMODE>
__global__ __launch_bounds__(256) void mfma_gemm2(const ushort* __restrict__ A, const ushort* __restrict__ Bt,
                                                  void* __restrict__ Cv,
                                                  const float* __restrict__ att_s, const float* __restrict__ att_d,
                                                  float* __restrict__ asrc, float* __restrict__ adst, int M) {
    __shared__ ushort Abuf[2][64 * 32];    // 2 x 4 KB
    __shared__ ushort Bbuf[2][128 * 32];   // 2 x 8 KB
    // bijective chunked swizzle (m204)
    const int nwg = gridDim.x;
    const int q = nwg >> 3, r = nwg & 7;
    const int orig = blockIdx.x;
    const int xcd = orig & 7, ii = orig >> 3;
    const int wgid = (xcd < r ? xcd * (q + 1) : r * (q + 1) + (xcd - r) * q) + ii;
    const int row0 = (wgid >> 2) * 64, col0 = (wgid & 3) * 128;

    const int t = threadIdx.x;
    const int wid = t >> 6, lane = t & 63;
    const int wr = wid >> 1, wc = wid & 1;          // 2 x 2 waves; wave = 32 rows x 64 cols
    const int l15 = lane & 15, l4 = lane >> 4;
    const int arow = t >> 2, kb = t & 3;            // staging coords: 64 rows x 4 chunks
    const int swz = (arow >> 1) & 3;
    const int ra = min(row0 + arow, M - 1);         // clamp (dup rows, stores guarded)
    const ushort* gA  = A + (size_t)ra * 512 + ((kb ^ swz) << 3);
    const ushort* gB0 = Bt + (size_t)(col0 + arow) * 512 + ((kb ^ swz) << 3);
    const ushort* gB1 = Bt + (size_t)(col0 + arow + 64) * 512 + ((kb ^ swz) << 3);  // same swz (row+64)
    f32x4 acc[2][4] = {};

    gload16(gA, &Abuf[0][wid * 512]);
    gload16(gB0, &Bbuf[0][wid * 512]);
    gload16(gB1, &Bbuf[0][2048 + wid * 512]);
    __syncthreads();
    int cur = 0;
    for (int k0 = 0; k0 < 512; k0 += 32) {
        if (k0 + 32 < 512) {
            gload16(gA + k0 + 32, &Abuf[cur ^ 1][wid * 512]);
            gload16(gB0 + k0 + 32, &Bbuf[cur ^ 1][wid * 512]);
            gload16(gB1 + k0 + 32, &Bbuf[cur ^ 1][2048 + wid * 512]);
        }
        bf16x8 af[2], bfr[4];
#pragma unroll
        for (int mr = 0; mr < 2; mr++) {
            int rr = wr * 32 + mr * 16 + l15;
            af[mr] = *(const bf16x8*)&Abuf[cur][rr * 32 + ((l4 ^ ((rr >> 1) & 3)) << 3)];
        }
#pragma unroll
        for (int nr = 0; nr < 4; nr++) {
            int cc = wc * 64 + nr * 16 + l15;
            bfr[nr] = *(const bf16x8*)&Bbuf[cur][cc * 32 + ((l4 ^ ((cc >> 1) & 3)) << 3)];
        }
#pragma unroll
        for (int mr = 0; mr < 2; mr++)
#pragma unroll
            for (int nr = 0; nr < 4; nr++)
                acc[mr][nr] = __builtin_amdgcn_mfma_f32_16x16x32_bf16(af[mr], bfr[nr], acc[mr][nr], 0, 0, 0);
        __syncthreads();
        cur ^= 1;
    }
    // C store
#pragma unroll
    for (int mr = 0; mr < 2; mr++) {
#pragma unroll
        for (int qq = 0; qq < 4; qq++) {
            int gr = row0 + wr * 32 + mr * 16 + l4 * 4 + qq;
            if (gr >= M) continue;
#pragma unroll
            for (int nr = 0; nr < 4; nr++) {
                int gc = col0 + wc * 64 + nr * 16 + l15;
                if (CMODE == 0) {
                    ((ushort*)Cv)[(size_t)gr * 512 + gc] = f2bf(acc[mr][nr][qq]);
                } else {
#if HAS_FP8
                    uint pk = __builtin_amdgcn_cvt_pk_fp8_f32(acc[mr][nr][qq], acc[mr][nr][qq], 0, false);
                    ((uchar*)Cv)[(size_t)gr * 512 + gc] = (uchar)(pk & 0xff);
#endif
                }
            }
        }
    }
    // fused alpha epilogue (no atomics): wave's 64 cols = head hd
    const int hd = ((wgid & 3) << 1) | wc;
    float asf[4], adf[4];
#pragma unroll
    for (int nr = 0; nr < 4; nr++) {
        asf[nr] = att_s[hd * 64 + nr * 16 + l15];
        adf[nr] = att_d[hd * 64 + nr * 16 + l15];
    }
#pragma unroll
    for (int mr = 0; mr < 2; mr++) {
#pragma unroll
        for (int qq = 0; qq < 4; qq++) {
            float s1 = 0.f, s2 = 0.f;
#pragma unroll
            for (int nr = 0; nr < 4; nr++) {
                s1 = fmaf(acc[mr][nr][qq], asf[nr], s1);
                s2 = fmaf(acc[mr][nr][qq], adf[nr], s2);
            }
#pragma unroll
            for (int st = 1; st < 16; st <<= 1) {
                s1 += __shfl_xor(s1, st);
                s2 += __shfl_xor(s2, st);
            }
            int gr = row0 + wr * 32 + mr * 16 + l4 * 4 + qq;
            if (gr < M && l15 == 0) { asrc[gr * 8 + hd] = s1; adst[gr * 8 + hd] = s2; }
        }
    }
}

// ---------------- MFMA layer-3 GEMM: h3[M,40] fp32 = A[M,512] @ Wt3^T ----------------
__global__ __launch_bounds__(256) void mfma_gemm3(const ushort* __restrict__ A, const ushort* __restrict__ Wt3,
                                                  float* __restrict__ h3, int M) {
    __shared__ ushort Abuf[2][64 * 32];
    __shared__ ushort Bbuf[2][64 * 32];
    const int t = threadIdx.x;
    const int wid = t >> 6, lane = t & 63;
    const int row0 = blockIdx.x * 64;
    const int l15 = lane & 15, l4 = lane >> 4;
    const int arow = t >> 2, kb = t & 3;
    const int swz = (arow >> 1) & 3;
    const int ra = min(row0 + arow, M - 1);
    const ushort* gA = A + (size_t)ra * 512 + ((kb ^ swz) << 3);
    const ushort* gB = Wt3 + (size_t)arow * 512 + ((kb ^ swz) << 3);
    f32x4 acc[4] = {};
    gload16(gA, &Abuf[0][wid * 512]);
    gload16(gB, &Bbuf[0][wid * 512]);
    __syncthreads();
    int cur = 0;
    for (int k0 = 0; k0 < 512; k0 += 32) {
        if (k0 + 32 < 512) {
            gload16(gA + k0 + 32, &Abuf[cur ^ 1][wid * 512]);
            gload16(gB + k0 + 32, &Bbuf[cur ^ 1][wid * 512]);
        }
        int rr = wid * 16 + l15;
        bf16x8 af = *(const bf16x8*)&Abuf[cur][rr * 32 + ((l4 ^ ((rr >> 1) & 3)) << 3)];
        bf16x8 bfr[4];
#pragma unroll
        for (int nr = 0; nr < 4; nr++) {
            int cc = nr * 16 + l15;
            bfr[nr] = *(const bf16x8*)&Bbuf[cur][cc * 32 + ((l4 ^ ((cc >> 1) & 3)) << 3)];
        }
#pragma unroll
        for (int nr = 0; nr < 4; nr++)
            acc[nr] = __builtin_amdgcn_mfma_f32_16x16x32_bf16(af, bfr[nr], acc[nr], 0, 0, 0);
        __syncthreads();
        cur ^= 1;
    }
#pragma unroll
    for (int qq = 0; qq < 4; qq++) {
        int gr = row0 + wid * 16 + l4 * 4 + qq;
        if (gr >= M) continue;
#pragma unroll
        for (int nr = 0; nr < 4; nr++) {
            int c = nr * 16 + l15;
            if (c < OUTC) h3[(size_t)gr * OUTC + c] = acc[nr][qq];
        }
    }
}

// ---------------- layer-3 alpha (h3 fp32, single head) ----------------
__global__ __launch_bounds__(256) void k_alpha1(const float* __restrict__ h, const float* __restrict__ att_s,
                                                const float* __restrict__ att_d, float* __restrict__ asrc,
                                                float* __restrict__ adst) {
    int gw = (blockIdx.x * 256 + threadIdx.x) >> 6;
    int lane = threadIdx.x & 63;
    if (gw >= NNODES) return;
    float s1 = 0.f, s2 = 0.f;
    if (lane < OUTC) {
        float v = h[(size_t)gw * OUTC + lane];
        s1 = v * att_s[lane];
        s2 = v * att_d[lane];
    }
#pragma unroll
    for (int m = 32; m > 0; m >>= 1) { s1 += __shfl_xor(s1, m); s2 += __shfl_xor(s2, m); }
    if (lane == 0) { asrc[gw] = s1; adst[gw] = s2; }
}

// ---------------- aggregation v4 (bf16 h) ----------------
template <bool DO_ELU>
__global__ __launch_bounds__(256) void agg_v4(const ushort* __restrict__ h, const float* __restrict__ asrc,
                                              const float* __restrict__ adst, const int* __restrict__ offs,
                                              const int* __restrict__ csr, const float* __restrict__ bias,
                                              const uint* __restrict__ mkeys, ushort* __restrict__ out) {
    const int wid = threadIdx.x >> 6, lane = threadIdx.x & 63;
    const int n = blockIdx.x * 4 + wid;
    if (n >= NNODES) return;
    const int beg = offs[n], deg = offs[n + 1] - beg;
    const int h8 = lane & 7;
    const int es = lane >> 3;
    const float ad_s = adst[n * 8 + h8];
    const float m8 = leaky(fdec(mkeys[h8]) + ad_s);

    float ss = 0.f;
    for (int i = es; i < deg; i += 8) {
        int s = csr[beg + i];
        ss += expf(leaky(asrc[s * 8 + h8] + ad_s) - m8);
    }
    ss += __shfl_xor(ss, 8);
    ss += __shfl_xor(ss, 16);
    ss += __shfl_xor(ss, 32);
    const float rs8 = 1.f / ss;

    const int hc = lane >> 3;
    float acc[8] = {0.f, 0.f, 0.f, 0.f, 0.f, 0.f, 0.f, 0.f};
    int base = 0;
    for (; base + 8 <= deg; base += 8) {
        int sv = csr[beg + base + es];
        float wv = expf(leaky(asrc[sv * 8 + h8] + ad_s) - m8) * rs8;
#pragma unroll
        for (int j = 0; j < 8; j++) {
            int src = (j << 3) | hc;
            float w = __shfl(wv, src);
            int s = __shfl(sv, src);
            bf16x8 hv = *(const bf16x8*)(h + (size_t)s * FINCH + lane * 8);
#pragma unroll
            for (int c = 0; c < 8; c++) acc[c] = fmaf(bf2f((ushort)hv[c]), w, acc[c]);
        }
    }
    if (base < deg) {
        int e = base + es;
        int sv = csr[beg + min(e, deg - 1)];
        float wv = (e < deg) ? expf(leaky(asrc[sv * 8 + h8] + ad_s) - m8) * rs8 : 0.f;
        int cnt = deg - base;
        for (int j = 0; j < cnt; j++) {
            int src = (j << 3) | hc;
            float w = __shfl(wv, src);
            int s = __shfl(sv, src);
            bf16x8 hv = *(const bf16x8*)(h + (size_t)s * FINCH + lane * 8);
#pragma unroll
            for (int c = 0; c < 8; c++) acc[c] = fmaf(bf2f((ushort)hv[c]), w, acc[c]);
        }
    }
    ushort o[8];
#pragma unroll
    for (int c = 0; c < 8; c++) {
        float v = acc[c] + bias[lane * 8 + c];
        if (DO_ELU) v = v > 0.f ? v : expf(v) - 1.f;
        o[c] = f2bf(v);
    }
    *(bf16x8*)(out + (size_t)n * FINCH + lane * 8) = *(bf16x8*)o;
}

#if HAS_FP8
// ---------------- aggregation v5 (fp8 h): same structure, HW fp8 decode ----------------
template <bool DO_ELU>
__global__ __launch_bounds__(256) void agg_v5(const uchar* __restrict__ h, const float* __restrict__ asrc,
                                              const float* __restrict__ adst, const int* __restrict__ offs,
                                              const int* __restrict__ csr, const float* __restrict__ bias,
                                              const uint* __restrict__ mkeys, ushort* __restrict__ out) {
    const int wid = threadIdx.x >> 6, lane = threadIdx.x & 63;
    const int n = blockIdx.x * 4 + wid;
    if (n >= NNODES) return;
    const int beg = offs[n], deg = offs[n + 1] - beg;
    const int h8 = lane & 7;
    const int es = lane >> 3;
    const float ad_s = adst[n * 8 + h8];
    const float m8 = leaky(fdec(mkeys[h8]) + ad_s);

    float ss = 0.f;
    for (int i = es; i < deg; i += 8) {
        int s = csr[beg + i];
        ss += expf(leaky(asrc[s * 8 + h8] + ad_s) - m8);
    }
    ss += __shfl_xor(ss, 8);
    ss += __shfl_xor(ss, 16);
    ss += __shfl_xor(ss, 32);
    const float rs8 = 1.f / ss;

    const int hc = lane >> 3;
    float acc[8] = {0.f, 0.f, 0.f, 0.f, 0.f, 0.f, 0.f, 0.f};
    int base = 0;
    for (; base + 8 <= deg; base += 8) {
        int sv = csr[beg + base + es];
        float wv = expf(leaky(asrc[sv * 8 + h8] + ad_s) - m8) * rs8;
#pragma unroll
        for (int j = 0; j < 8; j++) {
            int src = (j << 3) | hc;
            float w = __shfl(wv, src);
            int s = __shfl(sv, src);
            uint2 u = *(const uint2*)(h + (size_t)s * 512 + lane * 8);
            f32x2 p0 = __builtin_amdgcn_cvt_pk_f32_fp8(u.x, false);
            f32x2 p1 = __builtin_amdgcn_cvt_pk_f32_fp8(u.x, true);
            f32x2 p2 = __builtin_amdgcn_cvt_pk_f32_fp8(u.y, false);
            f32x2 p3 = __builtin_amdgcn_cvt_pk_f32_fp8(u.y, true);
            acc[0] = fmaf(p0[0], w, acc[0]); acc[1] = fmaf(p0[1], w, acc[1]);
            acc[2] = fmaf(p1[0], w, acc[2]); acc[3] = fmaf(p1[1], w, acc[3]);
            acc[4] = fmaf(p2[0], w, acc[4]); acc[5] = fmaf(p2[1], w, acc[5]);
            acc[6] = fmaf(p3[0], w, acc[6]); acc[7] = fmaf(p3[1], w, acc[7]);
        }
    }
    if (base < deg) {
        int e = base + es;
        int sv = csr[beg + min(e, deg - 1)];
        float wv = (e < deg) ? expf(leaky(asrc[sv * 8 + h8] + ad_s) - m8) * rs8 : 0.f;
        int cnt = deg - base;
        for (int j = 0; j < cnt; j++) {
            int src = (j << 3) | hc;
            float w = __shfl(wv, src);
            int s = __shfl(sv, src);
            uint2 u = *(const uint2*)(h + (size_t)s * 512 + lane * 8);
            f32x2 p0 = __builtin_amdgcn_cvt_pk_f32_fp8(u.x, false);
            f32x2 p1 = __builtin_amdgcn_cvt_pk_f32_fp8(u.x, true);
            f32x2 p2 = __builtin_amdgcn_cvt_pk_f32_fp8(u.y, false);
            f32x2 p3 = __builtin_amdgcn_cvt_pk_f32_fp8(u.y, true);
            acc[0] = fmaf(p0[0], w, acc[0]); acc[1] = fmaf(p0[1], w, acc[1]);
            acc[2] = fmaf(p1[0], w, acc[2]); acc[3] = fmaf(p1[1], w, acc[3]);
            acc[4] = fmaf(p2[0], w, acc[4]); acc[5] = fmaf(p2[1], w, acc[5]);
            acc[6] = fmaf(p3[0], w, acc[6]); acc[7] = fmaf(p3[1], w, acc[7]);
        }
    }
    ushort o[8];
#pragma unroll
    for (int c = 0; c < 8; c++) {
        float v = acc[c] + bias[lane * 8 + c];
        if (DO_ELU) v = v > 0.f ? v : expf(v) - 1.f;
        o[c] = f2bf(v);
    }
    *(bf16x8*)(out + (size_t)n * FINCH + lane * 8) = *(bf16x8*)o;
}
#endif

// ---------------- layer-3: one wave per node; agg + bias + log_softmax (fp32 out) ----------------
__global__ __launch_bounds__(64) void agg_out(const float* __restrict__ h3, const float* __restrict__ asrc,
                                              const float* __restrict__ adst, const int* __restrict__ offs,
                                              const int* __restrict__ csr, const float* __restrict__ bias,
                                              const uint* __restrict__ mkeys, float* __restrict__ out) {
    const int n = blockIdx.x, lane = threadIdx.x;
    const int beg = offs[n], deg = offs[n + 1] - beg;
    const float ad = adst[n];
    const float m = leaky(fdec(mkeys[0]) + ad);

    float ss = 0.f;
    for (int i = lane; i < deg; i += 64) ss += expf(leaky(asrc[csr[beg + i]] + ad) - m);
#pragma unroll
    for (int w = 32; w > 0; w >>= 1) ss += __shfl_xor(ss, w);
    float rs = 1.f / ss;

    float acc = 0.f;
    for (int base = 0; base < deg; base += 64) {
        int sv = (base + lane < deg) ? csr[beg + base + lane] : 0;
        int cnt = min(64, deg - base);
        int j = 0;
        for (; j + 2 <= cnt; j += 2) {
            int s0 = __shfl(sv, j), s1 = __shfl(sv, j + 1);
            float a0 = asrc[s0], a1 = asrc[s1];
            float v0 = (lane < OUTC) ? h3[(size_t)s0 * OUTC + lane] : 0.f;
            float v1 = (lane < OUTC) ? h3[(size_t)s1 * OUTC + lane] : 0.f;
            float w0 = expf(leaky(a0 + ad) - m) * rs;
            float w1 = expf(leaky(a1 + ad) - m) * rs;
            acc = fmaf(v0, w0, acc);
            acc = fmaf(v1, w1, acc);
        }
        if (j < cnt) {
            int s0 = __shfl(sv, j);
            float w0 = expf(leaky(asrc[s0] + ad) - m) * rs;
            float v0 = (lane < OUTC) ? h3[(size_t)s0 * OUTC + lane] : 0.f;
            acc = fmaf(v0, w0, acc);
        }
    }
    float v = (lane < OUTC) ? acc + bias[lane] : -1e30f;
    float mx = v;
#pragma unroll
    for (int w = 32; w > 0; w >>= 1) mx = fmaxf(mx, __shfl_xor(mx, w));
    float ex = (lane < OUTC) ? expf(v - mx) : 0.f;
    float se = ex;
#pragma unroll
    for (int w = 32; w > 0; w >>= 1) se += __shfl_xor(se, w);
    if (lane < OUTC) out[(size_t)n * OUTC + lane] = v - mx - logf(se);
}

extern "C" void kernel_launch(void* const* d_in, const int* in_sizes, int n_in,
                              void* d_out, int out_size, void* d_ws, size_t ws_size,
                              hipStream_t stream) {
    const float* x   = (const float*)d_in[0];
    const int*   ei  = (const int*)d_in[1];
    const float* W1  = (const float*)d_in[2];
    const float* as1 = (const float*)d_in[3];
    const float* ad1 = (const float*)d_in[4];
    const float* b1  = (const float*)d_in[5];
    const float* W2  = (const float*)d_in[6];
    const float* as2 = (const float*)d_in[7];
    const float* ad2 = (const float*)d_in[8];
    const float* b2  = (const float*)d_in[9];
    const float* W3  = (const float*)d_in[10];
    const float* as3 = (const float*)d_in[11];
    const float* ad3 = (const float*)d_in[12];
    const float* b3  = (const float*)d_in[13];
    float* out = (float*)d_out;

    // workspace (~111 MB; <= proven-safe 118 MB)
    char* p = (char*)d_ws;
    ushort* bufA = (ushort*)p; p += (size_t)NNODES * FINCH * 2;   // h1(fp8)/h2 bf16; h3 fp32
    ushort* bufB = (ushort*)p; p += (size_t)NNODES * FINCH * 2;   // x_bf16, then x2/x3 bf16
    float* asrc = (float*)p; p += (size_t)NNODES * 8 * 4;
    float* adst = (float*)p; p += (size_t)NNODES * 8 * 4;
    int* flag = (int*)p; p += 16;
    uint* mkeys = (uint*)p; p += 128;   // slots: 0..7 L1, 8..15 L2, 16 L3
    int* deg  = (int*)p; p += (size_t)NNODES * 4;
    int* offs = (int*)p; p += (size_t)(NNODES + 1) * 4;
    int* cur  = (int*)p; p += (size_t)NNODES * 4;
    int* csr  = (int*)p; p += (size_t)(NEDGES + NNODES) * 4;
    ushort* Wt1 = (ushort*)p; p += (size_t)512 * 512 * 2;
    ushort* Wt2 = (ushort*)p; p += (size_t)512 * 512 * 2;
    ushort* Wt3 = (ushort*)p; p += (size_t)64 * 512 * 2;
    int* bsum = (int*)p; p += (size_t)NSB * 4;
    int* bofs = (int*)p; p += (size_t)NSB * 4;
    float* h3 = (float*)bufA;
    float* asc3 = asrc;
    float* adc3 = adst;

    // graph build (CSR by dst, with self-loops)
    k_detect<<<1, 64, 0, stream>>>(ei, flag, mkeys);
    k_init_deg<<<(NNODES + 255) / 256, 256, 0, stream>>>(deg);
    k_count<<<(NEDGES + 255) / 256, 256, 0, stream>>>(ei, flag, deg);
    k_bsum<<<NSB, 256, 0, stream>>>(deg, bsum);
    k_bscan<<<1, 64, 0, stream>>>(bsum, bofs, offs);
    k_scan_final<<<NSB, 256, 0, stream>>>(deg, bofs, offs, cur);
    k_fill<<<(NEDGES + NNODES + 255) / 256, 256, 0, stream>>>(ei, flag, cur, csr);

    // precision prep
    {
        int n4 = NNODES * FINCH / 4;
        k_f2bf<<<(n4 + 255) / 256, 256, 0, stream>>>(x, bufB, n4);
        dim3 gt(16, 16);
        k_transpose<<<gt, 256, 0, stream>>>(W1, Wt1);
        k_transpose<<<gt, 256, 0, stream>>>(W2, Wt2);
        k_transpose3<<<128, 256, 0, stream>>>(W3, Wt3);
    }

    int nwg = 4 * ((NNODES + 63) / 64);   // 1D grid (64-row tiles x 4 col-tiles), swizzled in-kernel
    int gagg = (NNODES + 3) / 4;
#if HAS_FP8
    // layer 1: GEMM (+fused alpha) -> max -> agg (fp8 h1)
    mfma_gemm2<1><<<nwg, 256, 0, stream>>>(bufB, Wt1, bufA, as1, ad1, asrc, adst, NNODES);
    k_msrc<8><<<128, 256, 0, stream>>>(asrc, mkeys, NNODES * 8);
    agg_v5<true><<<gagg, 256, 0, stream>>>((const uchar*)bufA, asrc, adst, offs, csr, b1, mkeys, bufB);
#else
    mfma_gemm2<0><<<nwg, 256, 0, stream>>>(bufB, Wt1, bufA, as1, ad1, asrc, adst, NNODES);
    k_msrc<8><<<128, 256, 0, stream>>>(asrc, mkeys, NNODES * 8);
    agg_v4<true><<<gagg, 256, 0, stream>>>(bufA, asrc, adst, offs, csr, b1, mkeys, bufB);
#endif
    // layer 2 (bf16 h)
    mfma_gemm2<0><<<nwg, 256, 0, stream>>>(bufB, Wt2, bufA, as2, ad2, asrc, adst, NNODES);
    k_msrc<8><<<128, 256, 0, stream>>>(asrc, mkeys + 8, NNODES * 8);
    agg_v4<true><<<gagg, 256, 0, stream>>>(bufA, asrc, adst, offs, csr, b2, mkeys + 8, bufB);
    // layer 3
    mfma_gemm3<<<(NNODES + 63) / 64, 256, 0, stream>>>(bufB, Wt3, h3, NNODES);
    k_alpha1<<<(NNODES * 64 + 255) / 256, 256, 0, stream>>>(h3, as3, ad3, asc3, adc3);
    k_msrc<1><<<128, 256, 0, stream>>>(asc3, mkeys + 16, NNODES);
    agg_out<<<NNODES, 64, 0, stream>>>(h3, asc3, adc3, offs, csr, b3, mkeys + 16, out);
}

// Round 17
// 595.621 us; speedup vs baseline: 1.0246x; 1.0246x over previous
//
#include <hip/hip_runtime.h>
#include <math.h>

#define NNODES 50000
#define NEDGES 800000
#define FINCH 512
#define HIDC 64
#define NHEADS 8
#define OUTC 40
#define NSLOPE 0.2f
#define NSB ((NNODES + 255) / 256)

typedef unsigned short ushort;
typedef unsigned int uint;
typedef unsigned char uchar;
typedef __attribute__((ext_vector_type(8))) short bf16x8;
typedef __attribute__((ext_vector_type(4))) float f32x4;
typedef __attribute__((ext_vector_type(2))) float f32x2;

#if __has_builtin(__builtin_amdgcn_cvt_pk_f32_fp8) && __has_builtin(__builtin_amdgcn_cvt_pk_fp8_f32)
#define HAS_FP8 1
#else
#define HAS_FP8 0
#endif

static __device__ __forceinline__ float leaky(float e) { return e > 0.f ? e : NSLOPE * e; }

static __device__ __forceinline__ float bf2f(ushort u) {
    union { unsigned int i; float f; } c; c.i = ((unsigned int)u) << 16; return c.f;
}
static __device__ __forceinline__ ushort f2bf(float f) {
    union { float f; unsigned int i; } c; c.f = f;
    unsigned int r = c.i + 0x7FFF + ((c.i >> 16) & 1);  // round-nearest-even
    return (ushort)(r >> 16);
}
// order-preserving float<->uint key (for atomicMax on floats)
static __device__ __forceinline__ uint fkey(float f) {
    uint u = __float_as_uint(f);
    return (u & 0x80000000u) ? ~u : (u | 0x80000000u);
}
static __device__ __forceinline__ float fdec(uint k) {
    return __uint_as_float((k & 0x80000000u) ? (k & 0x7fffffffu) : ~k);
}

// async global->LDS 16B (wave-uniform LDS base + lane*16; per-lane global src)
static __device__ __forceinline__ void gload16(const ushort* g, ushort* l) {
    __builtin_amdgcn_global_load_lds((const __attribute__((address_space(1))) void*)g,
                                     (__attribute__((address_space(3))) void*)l, 16, 0, 0);
}

// ---------------- edge dtype detect + key init ----------------
__global__ __launch_bounds__(64) void k_detect(const int* __restrict__ ei, int* __restrict__ flag,
                                               uint* __restrict__ keys) {
    int lane = threadIdx.x;
    if (lane < 17) keys[lane] = fkey(-3.0e38f);
    int v = ei[2 * lane + 1];
    unsigned long long b = __ballot(v != 0);
    if (lane == 0) *flag = (b == 0ULL) ? 1 : 0;
}

static __device__ __forceinline__ int load_idx(const int* ei, int wide, int pos) {
    int v = wide ? ei[2 * (long long)pos] : ei[pos];
    v = v < 0 ? 0 : (v >= NNODES ? NNODES - 1 : v);
    return v;
}

// ---------------- graph build ----------------
__global__ void k_init_deg(int* __restrict__ deg) {
    int i = blockIdx.x * blockDim.x + threadIdx.x;
    if (i < NNODES) deg[i] = 1;  // self-loop
}

__global__ void k_count(const int* __restrict__ ei, const int* __restrict__ flag, int* __restrict__ deg) {
    int e = blockIdx.x * blockDim.x + threadIdx.x;
    if (e < NEDGES) {
        int d = load_idx(ei, *flag, NEDGES + e);
        atomicAdd(&deg[d], 1);
    }
}

__global__ __launch_bounds__(256) void k_bsum(const int* __restrict__ deg, int* __restrict__ bsum) {
    int i = blockIdx.x * 256 + threadIdx.x;
    int v = (i < NNODES) ? deg[i] : 0;
#pragma unroll
    for (int m = 32; m > 0; m >>= 1) v += __shfl_xor(v, m);
    __shared__ int ws[4];
    int wid = threadIdx.x >> 6, lane = threadIdx.x & 63;
    if (lane == 0) ws[wid] = v;
    __syncthreads();
    if (threadIdx.x == 0) bsum[blockIdx.x] = ws[0] + ws[1] + ws[2] + ws[3];
}

__global__ __launch_bounds__(64) void k_bscan(const int* __restrict__ bsum, int* __restrict__ bofs,
                                              int* __restrict__ offs) {
    const int lane = threadIdx.x;
    const int CH = (NSB + 63) / 64;
    int lo = lane * CH, hi = min(lo + CH, NSB);
    int s = 0;
    for (int i = lo; i < hi; i++) s += bsum[i];
    int x = s;
#pragma unroll
    for (int st = 1; st < 64; st <<= 1) { int v = __shfl_up(x, st); if (lane >= st) x += v; }
    int run = x - s;
    for (int i = lo; i < hi; i++) { bofs[i] = run; run += bsum[i]; }
    if (lane == 63) offs[NNODES] = run;
}

__global__ __launch_bounds__(256) void k_scan_final(const int* __restrict__ deg, const int* __restrict__ bofs,
                                                    int* __restrict__ offs, int* __restrict__ cur) {
    int b = blockIdx.x;
    int i = b * 256 + threadIdx.x;
    int v = (i < NNODES) ? deg[i] : 0;
    int lane = threadIdx.x & 63, wid = threadIdx.x >> 6;
    int x = v;
#pragma unroll
    for (int st = 1; st < 64; st <<= 1) { int t = __shfl_up(x, st); if (lane >= st) x += t; }
    __shared__ int ws[4];
    if (lane == 63) ws[wid] = x;
    __syncthreads();
    int wofs = 0;
#pragma unroll
    for (int w = 0; w < 4; w++) if (w < wid) wofs += ws[w];
    int excl = bofs[b] + wofs + x - v;
    if (i < NNODES) { offs[i] = excl; cur[i] = excl; }
}

__global__ void k_fill(const int* __restrict__ ei, const int* __restrict__ flag,
                       int* __restrict__ cur, int* __restrict__ csr) {
    int e = blockIdx.x * blockDim.x + threadIdx.x;
    if (e < NEDGES + NNODES) {
        int s, d;
        if (e < NEDGES) {
            int w = *flag;
            s = load_idx(ei, w, e);
            d = load_idx(ei, w, NEDGES + e);
        } else {
            s = e - NEDGES; d = s;
        }
        int pos = atomicAdd(&cur[d], 1);
        csr[pos] = s;
    }
}

// ---------------- per-head global max of src logits ----------------
template <int NH>
__global__ __launch_bounds__(256) void k_msrc(const float* __restrict__ src, uint* __restrict__ keys, int n) {
    float m = -3.0e38f;
    for (int i = blockIdx.x * 256 + threadIdx.x; i < n; i += gridDim.x * 256)
        m = fmaxf(m, src[i]);   // stride multiple of NH keeps head alignment
    __shared__ float red[256];
    red[threadIdx.x] = m;
    __syncthreads();
    for (int st = 128; st >= NH; st >>= 1) {
        if (threadIdx.x < st) red[threadIdx.x] = fmaxf(red[threadIdx.x], red[threadIdx.x + st]);
        __syncthreads();
    }
    if (threadIdx.x < NH) atomicMax(&keys[threadIdx.x], fkey(red[threadIdx.x]));
}

// ---------------- fp32 -> bf16 bulk convert ----------------
__global__ void k_f2bf(const float* __restrict__ in, ushort* __restrict__ out, int n4) {
    int i = blockIdx.x * blockDim.x + threadIdx.x;
    if (i < n4) {
        float4 v = ((const float4*)in)[i];
        ushort4 o = make_ushort4(f2bf(v.x), f2bf(v.y), f2bf(v.z), f2bf(v.w));
        ((ushort4*)out)[i] = o;
    }
}

// ---------------- W[512][512] fp32 -> Wt[512][512] bf16 transposed ----------------
__global__ __launch_bounds__(256) void k_transpose(const float* __restrict__ W, ushort* __restrict__ Wt) {
    __shared__ float tile[32][33];
    int bx = blockIdx.x, by = blockIdx.y;
    int tx = threadIdx.x & 31, ty = threadIdx.x >> 5;  // 32 x 8
#pragma unroll
    for (int i = 0; i < 4; i++)
        tile[ty + i * 8][tx] = W[(size_t)(by * 32 + ty + i * 8) * 512 + bx * 32 + tx];
    __syncthreads();
#pragma unroll
    for (int i = 0; i < 4; i++)
        Wt[(size_t)(bx * 32 + ty + i * 8) * 512 + by * 32 + tx] = f2bf(tile[tx][ty + i * 8]);
}

// ---------------- W3[512][40] fp32 -> Wt3[64][512] bf16 transposed, zero-padded ----------------
__global__ __launch_bounds__(256) void k_transpose3(const float* __restrict__ W3, ushort* __restrict__ Wt3) {
    int idx = blockIdx.x * 256 + threadIdx.x;   // 64*512 total
    int c = idx >> 9, k = idx & 511;
    Wt3[idx] = (c < OUTC) ? f2bf(W3[(size_t)k * OUTC + c]) : 0;
}

// ---------------- MFMA bf16 GEMM (layers 1-2): 128x128 tile, BK=32, 8 waves ----------------
// T4 counted-vmcnt pipeline: triple-buffered LDS, raw s_barrier, vmcnt(2) (never 0 in loop).
// XCD-swizzled; fused alpha epilogue (asrc/adst from fp32 acc, NO atomics).
// CMODE: 0 = bf16 C, 1 = fp8 e4m3 C.
template <int CMODE>
__global__ __launch_bounds__(512) void mfma_gemm2(const ushort* __restrict__ A, const ushort* __restrict__ Bt,
                                                  void* __restrict__ Cv,
                                                  const float* __restrict__ att_s, const float* __restrict__ att_d,
                                                  float* __restrict__ asrc, float* __restrict__ adst, int M) {
    __shared__ ushort Abuf[3][128 * 32];   // 3 x 8 KB
    __shared__ ushort Bbuf[3][128 * 32];
    // bijective chunked swizzle (m204)
    const int nwg = gridDim.x;
    const int q = nwg >> 3, r = nwg & 7;
    const int orig = blockIdx.x;
    const int xcd = orig & 7, ii = orig >> 3;
    const int wgid = (xcd < r ? xcd * (q + 1) : r * (q + 1) + (xcd - r) * q) + ii;
    const int row0 = (wgid >> 2) * 128, col0 = (wgid & 3) * 128;

    const int t = threadIdx.x;
    const int wid = t >> 6, lane = t & 63;
    const int wr = wid >> 1, wc = wid & 1;          // 4 x 2 waves
    const int l15 = lane & 15, l4 = lane >> 4;
    const int arow = t >> 2, kb = t & 3;            // staging coords
    const int swz = (arow >> 1) & 3;
    const int ra = min(row0 + arow, M - 1);         // clamp (dup rows, stores guarded)
    const ushort* gA = A + (size_t)ra * 512 + ((kb ^ swz) << 3);
    const ushort* gB = Bt + (size_t)(col0 + arow) * 512 + ((kb ^ swz) << 3);
    f32x4 acc[2][4] = {};

    // prologue: stage K-steps 0 and 1 (2 loads/thread each)
    gload16(gA, &Abuf[0][wid * 512]);
    gload16(gB, &Bbuf[0][wid * 512]);
    gload16(gA + 32, &Abuf[1][wid * 512]);
    gload16(gB + 32, &Bbuf[1][wid * 512]);

#pragma unroll
    for (int i = 0; i < 16; i++) {
        const int cur = i % 3;
        // own step-i loads done; step-(i+1)'s 2 loads stay in flight across the barrier
        if (i < 15) asm volatile("s_waitcnt vmcnt(2)" ::: "memory");
        else        asm volatile("s_waitcnt vmcnt(0)" ::: "memory");
        __builtin_amdgcn_s_barrier();
        __builtin_amdgcn_sched_barrier(0);   // pin: no LDS reads hoist above the barrier
        if (i + 2 < 16) {
            const int nb = (i + 2) % 3;      // buffer read in step i-1; all readers passed barrier_i
            gload16(gA + (i + 2) * 32, &Abuf[nb][wid * 512]);
            gload16(gB + (i + 2) * 32, &Bbuf[nb][wid * 512]);
        }
        bf16x8 af[2], bfr[4];
#pragma unroll
        for (int mr = 0; mr < 2; mr++) {
            int rr = wr * 32 + mr * 16 + l15;
            af[mr] = *(const bf16x8*)&Abuf[cur][rr * 32 + ((l4 ^ ((rr >> 1) & 3)) << 3)];
        }
#pragma unroll
        for (int nr = 0; nr < 4; nr++) {
            int cc = wc * 64 + nr * 16 + l15;
            bfr[nr] = *(const bf16x8*)&Bbuf[cur][cc * 32 + ((l4 ^ ((cc >> 1) & 3)) << 3)];
        }
#pragma unroll
        for (int mr = 0; mr < 2; mr++)
#pragma unroll
            for (int nr = 0; nr < 4; nr++)
                acc[mr][nr] = __builtin_amdgcn_mfma_f32_16x16x32_bf16(af[mr], bfr[nr], acc[mr][nr], 0, 0, 0);
    }
    // C store
#pragma unroll
    for (int mr = 0; mr < 2; mr++) {
#pragma unroll
        for (int qq = 0; qq < 4; qq++) {
            int gr = row0 + wr * 32 + mr * 16 + l4 * 4 + qq;
            if (gr >= M) continue;
#pragma unroll
            for (int nr = 0; nr < 4; nr++) {
                int gc = col0 + wc * 64 + nr * 16 + l15;
                if (CMODE == 0) {
                    ((ushort*)Cv)[(size_t)gr * 512 + gc] = f2bf(acc[mr][nr][qq]);
                } else {
#if HAS_FP8
                    uint pk = __builtin_amdgcn_cvt_pk_fp8_f32(acc[mr][nr][qq], acc[mr][nr][qq], 0, false);
                    ((uchar*)Cv)[(size_t)gr * 512 + gc] = (uchar)(pk & 0xff);
#endif
                }
            }
        }
    }
    // fused alpha epilogue (no atomics): wave's 64 cols = head hd
    const int hd = ((wgid & 3) << 1) | wc;
    float asf[4], adf[4];
#pragma unroll
    for (int nr = 0; nr < 4; nr++) {
        asf[nr] = att_s[hd * 64 + nr * 16 + l15];
        adf[nr] = att_d[hd * 64 + nr * 16 + l15];
    }
#pragma unroll
    for (int mr = 0; mr < 2; mr++) {
#pragma unroll
        for (int qq = 0; qq < 4; qq++) {
            float s1 = 0.f, s2 = 0.f;
#pragma unroll
            for (int nr = 0; nr < 4; nr++) {
                s1 = fmaf(acc[mr][nr][qq], asf[nr], s1);
                s2 = fmaf(acc[mr][nr][qq], adf[nr], s2);
            }
#pragma unroll
            for (int st = 1; st < 16; st <<= 1) {
                s1 += __shfl_xor(s1, st);
                s2 += __shfl_xor(s2, st);
            }
            int gr = row0 + wr * 32 + mr * 16 + l4 * 4 + qq;
            if (gr < M && l15 == 0) { asrc[gr * 8 + hd] = s1; adst[gr * 8 + hd] = s2; }
        }
    }
}

// ---------------- MFMA layer-3 GEMM: h3[M,40] fp32 = A[M,512] @ Wt3^T ----------------
__global__ __launch_bounds__(256) void mfma_gemm3(const ushort* __restrict__ A, const ushort* __restrict__ Wt3,
                                                  float* __restrict__ h3, int M) {
    __shared__ ushort Abuf[2][64 * 32];
    __shared__ ushort Bbuf[2][64 * 32];
    const int t = threadIdx.x;
    const int wid = t >> 6, lane = t & 63;
    const int row0 = blockIdx.x * 64;
    const int l15 = lane & 15, l4 = lane >> 4;
    const int arow = t >> 2, kb = t & 3;
    const int swz = (arow >> 1) & 3;
    const int ra = min(row0 + arow, M - 1);
    const ushort* gA = A + (size_t)ra * 512 + ((kb ^ swz) << 3);
    const ushort* gB = Wt3 + (size_t)arow * 512 + ((kb ^ swz) << 3);
    f32x4 acc[4] = {};
    gload16(gA, &Abuf[0][wid * 512]);
    gload16(gB, &Bbuf[0][wid * 512]);
    __syncthreads();
    int cur = 0;
    for (int k0 = 0; k0 < 512; k0 += 32) {
        if (k0 + 32 < 512) {
            gload16(gA + k0 + 32, &Abuf[cur ^ 1][wid * 512]);
            gload16(gB + k0 + 32, &Bbuf[cur ^ 1][wid * 512]);
        }
        int rr = wid * 16 + l15;
        bf16x8 af = *(const bf16x8*)&Abuf[cur][rr * 32 + ((l4 ^ ((rr >> 1) & 3)) << 3)];
        bf16x8 bfr[4];
#pragma unroll
        for (int nr = 0; nr < 4; nr++) {
            int cc = nr * 16 + l15;
            bfr[nr] = *(const bf16x8*)&Bbuf[cur][cc * 32 + ((l4 ^ ((cc >> 1) & 3)) << 3)];
        }
#pragma unroll
        for (int nr = 0; nr < 4; nr++)
            acc[nr] = __builtin_amdgcn_mfma_f32_16x16x32_bf16(af, bfr[nr], acc[nr], 0, 0, 0);
        __syncthreads();
        cur ^= 1;
    }
#pragma unroll
    for (int qq = 0; qq < 4; qq++) {
        int gr = row0 + wid * 16 + l4 * 4 + qq;
        if (gr >= M) continue;
#pragma unroll
        for (int nr = 0; nr < 4; nr++) {
            int c = nr * 16 + l15;
            if (c < OUTC) h3[(size_t)gr * OUTC + c] = acc[nr][qq];
        }
    }
}

// ---------------- layer-3 alpha (h3 fp32, single head) ----------------
__global__ __launch_bounds__(256) void k_alpha1(const float* __restrict__ h, const float* __restrict__ att_s,
                                                const float* __restrict__ att_d, float* __restrict__ asrc,
                                                float* __restrict__ adst) {
    int gw = (blockIdx.x * 256 + threadIdx.x) >> 6;
    int lane = threadIdx.x & 63;
    if (gw >= NNODES) return;
    float s1 = 0.f, s2 = 0.f;
    if (lane < OUTC) {
        float v = h[(size_t)gw * OUTC + lane];
        s1 = v * att_s[lane];
        s2 = v * att_d[lane];
    }
#pragma unroll
    for (int m = 32; m > 0; m >>= 1) { s1 += __shfl_xor(s1, m); s2 += __shfl_xor(s2, m); }
    if (lane == 0) { asrc[gw] = s1; adst[gw] = s2; }
}

// ---------------- aggregation v4 (bf16 h) ----------------
template <bool DO_ELU>
__global__ __launch_bounds__(256) void agg_v4(const ushort* __restrict__ h, const float* __restrict__ asrc,
                                              const float* __restrict__ adst, const int* __restrict__ offs,
                                              const int* __restrict__ csr, const float* __restrict__ bias,
                                              const uint* __restrict__ mkeys, ushort* __restrict__ out) {
    const int wid = threadIdx.x >> 6, lane = threadIdx.x & 63;
    const int n = blockIdx.x * 4 + wid;
    if (n >= NNODES) return;
    const int beg = offs[n], deg = offs[n + 1] - beg;
    const int h8 = lane & 7;
    const int es = lane >> 3;
    const float ad_s = adst[n * 8 + h8];
    const float m8 = leaky(fdec(mkeys[h8]) + ad_s);

    float ss = 0.f;
    for (int i = es; i < deg; i += 8) {
        int s = csr[beg + i];
        ss += expf(leaky(asrc[s * 8 + h8] + ad_s) - m8);
    }
    ss += __shfl_xor(ss, 8);
    ss += __shfl_xor(ss, 16);
    ss += __shfl_xor(ss, 32);
    const float rs8 = 1.f / ss;

    const int hc = lane >> 3;
    float acc[8] = {0.f, 0.f, 0.f, 0.f, 0.f, 0.f, 0.f, 0.f};
    int base = 0;
    for (; base + 8 <= deg; base += 8) {
        int sv = csr[beg + base + es];
        float wv = expf(leaky(asrc[sv * 8 + h8] + ad_s) - m8) * rs8;
#pragma unroll
        for (int j = 0; j < 8; j++) {
            int src = (j << 3) | hc;
            float w = __shfl(wv, src);
            int s = __shfl(sv, src);
            bf16x8 hv = *(const bf16x8*)(h + (size_t)s * FINCH + lane * 8);
#pragma unroll
            for (int c = 0; c < 8; c++) acc[c] = fmaf(bf2f((ushort)hv[c]), w, acc[c]);
        }
    }
    if (base < deg) {
        int e = base + es;
        int sv = csr[beg + min(e, deg - 1)];
        float wv = (e < deg) ? expf(leaky(asrc[sv * 8 + h8] + ad_s) - m8) * rs8 : 0.f;
        int cnt = deg - base;
        for (int j = 0; j < cnt; j++) {
            int src = (j << 3) | hc;
            float w = __shfl(wv, src);
            int s = __shfl(sv, src);
            bf16x8 hv = *(const bf16x8*)(h + (size_t)s * FINCH + lane * 8);
#pragma unroll
            for (int c = 0; c < 8; c++) acc[c] = fmaf(bf2f((ushort)hv[c]), w, acc[c]);
        }
    }
    ushort o[8];
#pragma unroll
    for (int c = 0; c < 8; c++) {
        float v = acc[c] + bias[lane * 8 + c];
        if (DO_ELU) v = v > 0.f ? v : expf(v) - 1.f;
        o[c] = f2bf(v);
    }
    *(bf16x8*)(out + (size_t)n * FINCH + lane * 8) = *(bf16x8*)o;
}

#if HAS_FP8
// ---------------- aggregation v5 (fp8 h): same structure, HW fp8 decode ----------------
template <bool DO_ELU>
__global__ __launch_bounds__(256) void agg_v5(const uchar* __restrict__ h, const float* __restrict__ asrc,
                                              const float* __restrict__ adst, const int* __restrict__ offs,
                                              const int* __restrict__ csr, const float* __restrict__ bias,
                                              const uint* __restrict__ mkeys, ushort* __restrict__ out) {
    const int wid = threadIdx.x >> 6, lane = threadIdx.x & 63;
    const int n = blockIdx.x * 4 + wid;
    if (n >= NNODES) return;
    const int beg = offs[n], deg = offs[n + 1] - beg;
    const int h8 = lane & 7;
    const int es = lane >> 3;
    const float ad_s = adst[n * 8 + h8];
    const float m8 = leaky(fdec(mkeys[h8]) + ad_s);

    float ss = 0.f;
    for (int i = es; i < deg; i += 8) {
        int s = csr[beg + i];
        ss += expf(leaky(asrc[s * 8 + h8] + ad_s) - m8);
    }
    ss += __shfl_xor(ss, 8);
    ss += __shfl_xor(ss, 16);
    ss += __shfl_xor(ss, 32);
    const float rs8 = 1.f / ss;

    const int hc = lane >> 3;
    float acc[8] = {0.f, 0.f, 0.f, 0.f, 0.f, 0.f, 0.f, 0.f};
    int base = 0;
    for (; base + 8 <= deg; base += 8) {
        int sv = csr[beg + base + es];
        float wv = expf(leaky(asrc[sv * 8 + h8] + ad_s) - m8) * rs8;
#pragma unroll
        for (int j = 0; j < 8; j++) {
            int src = (j << 3) | hc;
            float w = __shfl(wv, src);
            int s = __shfl(sv, src);
            uint2 u = *(const uint2*)(h + (size_t)s * 512 + lane * 8);
            f32x2 p0 = __builtin_amdgcn_cvt_pk_f32_fp8(u.x, false);
            f32x2 p1 = __builtin_amdgcn_cvt_pk_f32_fp8(u.x, true);
            f32x2 p2 = __builtin_amdgcn_cvt_pk_f32_fp8(u.y, false);
            f32x2 p3 = __builtin_amdgcn_cvt_pk_f32_fp8(u.y, true);
            acc[0] = fmaf(p0[0], w, acc[0]); acc[1] = fmaf(p0[1], w, acc[1]);
            acc[2] = fmaf(p1[0], w, acc[2]); acc[3] = fmaf(p1[1], w, acc[3]);
            acc[4] = fmaf(p2[0], w, acc[4]); acc[5] = fmaf(p2[1], w, acc[5]);
            acc[6] = fmaf(p3[0], w, acc[6]); acc[7] = fmaf(p3[1], w, acc[7]);
        }
    }
    if (base < deg) {
        int e = base + es;
        int sv = csr[beg + min(e, deg - 1)];
        float wv = (e < deg) ? expf(leaky(asrc[sv * 8 + h8] + ad_s) - m8) * rs8 : 0.f;
        int cnt = deg - base;
        for (int j = 0; j < cnt; j++) {
            int src = (j << 3) | hc;
            float w = __shfl(wv, src);
            int s = __shfl(sv, src);
            uint2 u = *(const uint2*)(h + (size_t)s * 512 + lane * 8);
            f32x2 p0 = __builtin_amdgcn_cvt_pk_f32_fp8(u.x, false);
            f32x2 p1 = __builtin_amdgcn_cvt_pk_f32_fp8(u.x, true);
            f32x2 p2 = __builtin_amdgcn_cvt_pk_f32_fp8(u.y, false);
            f32x2 p3 = __builtin_amdgcn_cvt_pk_f32_fp8(u.y, true);
            acc[0] = fmaf(p0[0], w, acc[0]); acc[1] = fmaf(p0[1], w, acc[1]);
            acc[2] = fmaf(p1[0], w, acc[2]); acc[3] = fmaf(p1[1], w, acc[3]);
            acc[4] = fmaf(p2[0], w, acc[4]); acc[5] = fmaf(p2[1], w, acc[5]);
            acc[6] = fmaf(p3[0], w, acc[6]); acc[7] = fmaf(p3[1], w, acc[7]);
        }
    }
    ushort o[8];
#pragma unroll
    for (int c = 0; c < 8; c++) {
        float v = acc[c] + bias[lane * 8 + c];
        if (DO_ELU) v = v > 0.f ? v : expf(v) - 1.f;
        o[c] = f2bf(v);
    }
    *(bf16x8*)(out + (size_t)n * FINCH + lane * 8) = *(bf16x8*)o;
}
#endif

// ---------------- layer-3: one wave per node; agg + bias + log_softmax (fp32 out) ----------------
__global__ __launch_bounds__(64) void agg_out(const float* __restrict__ h3, const float* __restrict__ asrc,
                                              const float* __restrict__ adst, const int* __restrict__ offs,
                                              const int* __restrict__ csr, const float* __restrict__ bias,
                                              const uint* __restrict__ mkeys, float* __restrict__ out) {
    const int n = blockIdx.x, lane = threadIdx.x;
    const int beg = offs[n], deg = offs[n + 1] - beg;
    const float ad = adst[n];
    const float m = leaky(fdec(mkeys[0]) + ad);

    float ss = 0.f;
    for (int i = lane; i < deg; i += 64) ss += expf(leaky(asrc[csr[beg + i]] + ad) - m);
#pragma unroll
    for (int w = 32; w > 0; w >>= 1) ss += __shfl_xor(ss, w);
    float rs = 1.f / ss;

    float acc = 0.f;
    for (int base = 0; base < deg; base += 64) {
        int sv = (base + lane < deg) ? csr[beg + base + lane] : 0;
        int cnt = min(64, deg - base);
        int j = 0;
        for (; j + 2 <= cnt; j += 2) {
            int s0 = __shfl(sv, j), s1 = __shfl(sv, j + 1);
            float a0 = asrc[s0], a1 = asrc[s1];
            float v0 = (lane < OUTC) ? h3[(size_t)s0 * OUTC + lane] : 0.f;
            float v1 = (lane < OUTC) ? h3[(size_t)s1 * OUTC + lane] : 0.f;
            float w0 = expf(leaky(a0 + ad) - m) * rs;
            float w1 = expf(leaky(a1 + ad) - m) * rs;
            acc = fmaf(v0, w0, acc);
            acc = fmaf(v1, w1, acc);
        }
        if (j < cnt) {
            int s0 = __shfl(sv, j);
            float w0 = expf(leaky(asrc[s0] + ad) - m) * rs;
            float v0 = (lane < OUTC) ? h3[(size_t)s0 * OUTC + lane] : 0.f;
            acc = fmaf(v0, w0, acc);
        }
    }
    float v = (lane < OUTC) ? acc + bias[lane] : -1e30f;
    float mx = v;
#pragma unroll
    for (int w = 32; w > 0; w >>= 1) mx = fmaxf(mx, __shfl_xor(mx, w));
    float ex = (lane < OUTC) ? expf(v - mx) : 0.f;
    float se = ex;
#pragma unroll
    for (int w = 32; w > 0; w >>= 1) se += __shfl_xor(se, w);
    if (lane < OUTC) out[(size_t)n * OUTC + lane] = v - mx - logf(se);
}

extern "C" void kernel_launch(void* const* d_in, const int* in_sizes, int n_in,
                              void* d_out, int out_size, void* d_ws, size_t ws_size,
                              hipStream_t stream) {
    const float* x   = (const float*)d_in[0];
    const int*   ei  = (const int*)d_in[1];
    const float* W1  = (const float*)d_in[2];
    const float* as1 = (const float*)d_in[3];
    const float* ad1 = (const float*)d_in[4];
    const float* b1  = (const float*)d_in[5];
    const float* W2  = (const float*)d_in[6];
    const float* as2 = (const float*)d_in[7];
    const float* ad2 = (const float*)d_in[8];
    const float* b2  = (const float*)d_in[9];
    const float* W3  = (const float*)d_in[10];
    const float* as3 = (const float*)d_in[11];
    const float* ad3 = (const float*)d_in[12];
    const float* b3  = (const float*)d_in[13];
    float* out = (float*)d_out;

    // workspace (~111 MB; <= proven-safe 118 MB)
    char* p = (char*)d_ws;
    ushort* bufA = (ushort*)p; p += (size_t)NNODES * FINCH * 2;   // h1(fp8)/h2 bf16; h3 fp32
    ushort* bufB = (ushort*)p; p += (size_t)NNODES * FINCH * 2;   // x_bf16, then x2/x3 bf16
    float* asrc = (float*)p; p += (size_t)NNODES * 8 * 4;
    float* adst = (float*)p; p += (size_t)NNODES * 8 * 4;
    int* flag = (int*)p; p += 16;
    uint* mkeys = (uint*)p; p += 128;   // slots: 0..7 L1, 8..15 L2, 16 L3
    int* deg  = (int*)p; p += (size_t)NNODES * 4;
    int* offs = (int*)p; p += (size_t)(NNODES + 1) * 4;
    int* cur  = (int*)p; p += (size_t)NNODES * 4;
    int* csr  = (int*)p; p += (size_t)(NEDGES + NNODES) * 4;
    ushort* Wt1 = (ushort*)p; p += (size_t)512 * 512 * 2;
    ushort* Wt2 = (ushort*)p; p += (size_t)512 * 512 * 2;
    ushort* Wt3 = (ushort*)p; p += (size_t)64 * 512 * 2;
    int* bsum = (int*)p; p += (size_t)NSB * 4;
    int* bofs = (int*)p; p += (size_t)NSB * 4;
    float* h3 = (float*)bufA;
    float* asc3 = asrc;
    float* adc3 = adst;

    // graph build (CSR by dst, with self-loops)
    k_detect<<<1, 64, 0, stream>>>(ei, flag, mkeys);
    k_init_deg<<<(NNODES + 255) / 256, 256, 0, stream>>>(deg);
    k_count<<<(NEDGES + 255) / 256, 256, 0, stream>>>(ei, flag, deg);
    k_bsum<<<NSB, 256, 0, stream>>>(deg, bsum);
    k_bscan<<<1, 64, 0, stream>>>(bsum, bofs, offs);
    k_scan_final<<<NSB, 256, 0, stream>>>(deg, bofs, offs, cur);
    k_fill<<<(NEDGES + NNODES + 255) / 256, 256, 0, stream>>>(ei, flag, cur, csr);

    // precision prep
    {
        int n4 = NNODES * FINCH / 4;
        k_f2bf<<<(n4 + 255) / 256, 256, 0, stream>>>(x, bufB, n4);
        dim3 gt(16, 16);
        k_transpose<<<gt, 256, 0, stream>>>(W1, Wt1);
        k_transpose<<<gt, 256, 0, stream>>>(W2, Wt2);
        k_transpose3<<<128, 256, 0, stream>>>(W3, Wt3);
    }

    int nwg = 4 * ((NNODES + 127) / 128);   // 1D grid (128x128 tiles), swizzled in-kernel
    int gagg = (NNODES + 3) / 4;
#if HAS_FP8
    // layer 1: GEMM (+fused alpha) -> max -> agg (fp8 h1)
    mfma_gemm2<1><<<nwg, 512, 0, stream>>>(bufB, Wt1, bufA, as1, ad1, asrc, adst, NNODES);
    k_msrc<8><<<128, 256, 0, stream>>>(asrc, mkeys, NNODES * 8);
    agg_v5<true><<<gagg, 256, 0, stream>>>((const uchar*)bufA, asrc, adst, offs, csr, b1, mkeys, bufB);
#else
    mfma_gemm2<0><<<nwg, 512, 0, stream>>>(bufB, Wt1, bufA, as1, ad1, asrc, adst, NNODES);
    k_msrc<8><<<128, 256, 0, stream>>>(asrc, mkeys, NNODES * 8);
    agg_v4<true><<<gagg, 256, 0, stream>>>(bufA, asrc, adst, offs, csr, b1, mkeys, bufB);
#endif
    // layer 2 (bf16 h)
    mfma_gemm2<0><<<nwg, 512, 0, stream>>>(bufB, Wt2, bufA, as2, ad2, asrc, adst, NNODES);
    k_msrc<8><<<128, 256, 0, stream>>>(asrc, mkeys + 8, NNODES * 8);
    agg_v4<true><<<gagg, 256, 0, stream>>>(bufA, asrc, adst, offs, csr, b2, mkeys + 8, bufB);
    // layer 3
    mfma_gemm3<<<(NNODES + 63) / 64, 256, 0, stream>>>(bufB, Wt3, h3, NNODES);
    k_alpha1<<<(NNODES * 64 + 255) / 256, 256, 0, stream>>>(h3, as3, ad3, asc3, adc3);
    k_msrc<1><<<128, 256, 0, stream>>>(asc3, mkeys + 16, NNODES);
    agg_out<<<NNODES, 64, 0, stream>>>(h3, asc3, adc3, offs, csr, b3, mkeys + 16, out);
}